// Round 13
// baseline (328.831 us; speedup 1.0000x reference)
//
#include <hip/hip_runtime.h>
#include <hip/hip_fp16.h>
#include <cstdint>
#include <cstddef>

// GAT 3-layer forward for MI355X — round 13.
// Changes vs round 12 (299us):
//  * k_fused256 decode: v_cvt_pk_f32_fp8 (2 fp8 -> float2) + float2
//    accumulators (v_pk_fma_f32) — 8 packed cvt + 8 packed FMA per edge-lane
//    instead of 16 scalar cvt + 16 scalar FMA. Round 12 showed the kernel
//    moved off the byte ceiling (3.9 B/cy/CU, VALU 66%) onto decode VALU.
//    Decoded values bit-identical (same HW converter) -> absmax unchanged.

#define IN_FEATS 128

typedef _Float16 f16x8 __attribute__((ext_vector_type(8)));
typedef float f32x4 __attribute__((ext_vector_type(4)));
typedef float f32x2 __attribute__((ext_vector_type(2)));

// ---------- fp8 helpers (HW cvt; self-consistent encode/decode) ----------
__device__ __forceinline__ unsigned char f32_to_fp8(float f) {
    int p = __builtin_amdgcn_cvt_pk_fp8_f32(f, 0.f, 0, false);
    return (unsigned char)(p & 0xff);
}
// accumulate one edge's 16 fp8 channels (q) into a[8] (f32x2) with weight w
__device__ __forceinline__ void acc_edge(f32x2* a, uint4 q, float w) {
    f32x2 w2 = {w, w};
    a[0] += w2 * __builtin_amdgcn_cvt_pk_f32_fp8((int)q.x, false);
    a[1] += w2 * __builtin_amdgcn_cvt_pk_f32_fp8((int)q.x, true);
    a[2] += w2 * __builtin_amdgcn_cvt_pk_f32_fp8((int)q.y, false);
    a[3] += w2 * __builtin_amdgcn_cvt_pk_f32_fp8((int)q.y, true);
    a[4] += w2 * __builtin_amdgcn_cvt_pk_f32_fp8((int)q.z, false);
    a[5] += w2 * __builtin_amdgcn_cvt_pk_f32_fp8((int)q.z, true);
    a[6] += w2 * __builtin_amdgcn_cvt_pk_f32_fp8((int)q.w, false);
    a[7] += w2 * __builtin_amdgcn_cvt_pk_f32_fp8((int)q.w, true);
}

// ---------- fused: weight prep (blocks 0..455) ∥ degree+rank (rest) ----------
__global__ __launch_bounds__(256) void k_degprep(
    const float* __restrict__ W0, const float* __restrict__ W1, const float* __restrict__ W2,
    const float* __restrict__ al0, const float* __restrict__ ar0,
    const float* __restrict__ al1, const float* __restrict__ ar1,
    const float* __restrict__ al2, const float* __restrict__ ar2,
    _Float16* __restrict__ W0T, _Float16* __restrict__ W1T, _Float16* __restrict__ W2T,
    _Float16* __restrict__ WLR0, _Float16* __restrict__ WLR1, _Float16* __restrict__ WLR2,
    const int* __restrict__ dst, int* __restrict__ deg, int* __restrict__ rank, int E) {
    int bid = blockIdx.x, t = threadIdx.x;
    if (bid >= 456) {                      // degree count + rank (rank write coalesced)
        int e = (bid - 456) * 256 + t;
        if (e < E) rank[e] = atomicAdd(deg + dst[e], 1);
        return;
    }
    if (bid < 128) {                       // W0T [256][128]
        int i = bid * 256 + t;
        int nn = i >> 7, kk = i & 127;
        W0T[i] = (_Float16)W0[(size_t)kk * 256 + nn];
    } else if (bid < 384) {                // W1T [256][256]
        int i = (bid - 128) * 256 + t;
        int nn = i >> 8, kk = i & 255;
        W1T[i] = (_Float16)W1[(size_t)kk * 256 + nn];
    } else if (bid < 416) {                // W2T [32][256]
        int i = (bid - 384) * 256 + t;
        int nn = i >> 8, kk = i & 255;
        W2T[i] = (_Float16)W2[(size_t)kk * 32 + nn];
    } else if (bid < 424) {                // WLR0 [16][128]
        int i = (bid - 416) * 256 + t;
        int j = i >> 7, k = i & 127;
        int h = j & 7;
        const float* av = (j < 8) ? al0 : ar0;
        float sum = 0.f;
        #pragma unroll 8
        for (int c = 0; c < 32; ++c) sum += W0[(size_t)k * 256 + h * 32 + c] * av[h * 32 + c];
        WLR0[i] = (_Float16)sum;
    } else if (bid < 440) {                // WLR1 [16][256]
        int i = (bid - 424) * 256 + t;
        int j = i >> 8, k = i & 255;
        int h = j & 7;
        const float* av = (j < 8) ? al1 : ar1;
        float sum = 0.f;
        #pragma unroll 8
        for (int c = 0; c < 32; ++c) sum += W1[(size_t)k * 256 + h * 32 + c] * av[h * 32 + c];
        WLR1[i] = (_Float16)sum;
    } else {                               // WLR2 [16][256]
        int i = (bid - 440) * 256 + t;
        int j = i >> 8, k = i & 255;
        float sum = 0.f;
        if (j < 2) {
            const float* av = (j == 0) ? al2 : ar2;
            #pragma unroll 8
            for (int c = 0; c < 32; ++c) sum += W2[(size_t)k * 32 + c] * av[c];
        }
        WLR2[i] = (_Float16)sum;
    }
}

// ---------- fused: layer-0 GEMM (blocks < GB) ∥ atomic-free CSR fill ----------
__global__ __launch_bounds__(256) void k_gemm0_fill(
    const float* __restrict__ A, const _Float16* __restrict__ BT,
    const _Float16* __restrict__ WLRT, unsigned char* __restrict__ C8,
    float* __restrict__ el, float* __restrict__ er, int M, int GB,
    const int* __restrict__ dst, const int* __restrict__ src,
    const int* __restrict__ row_ptr, const int* __restrict__ rank,
    int* __restrict__ csrc, int E) {
    const int K = 128, N = 256, LDA = K + 8;
    __shared__ _Float16 As[64 * LDA];
    int tid = threadIdx.x;
    if ((int)blockIdx.x >= GB) {           // ---- fill branch: 4 edges/thread ----
        int base = ((int)blockIdx.x - GB) * 1024 + tid;
        #pragma unroll
        for (int i = 0; i < 4; ++i) {
            int e = base + i * 256;
            if (e < E) {
                int d = dst[e];
                csrc[row_ptr[d] + rank[e]] = src[e];
            }
        }
        return;
    }
    // ---- GEMM branch (K=128, A fp32 cast in staging) ----
    int lane = tid & 63, wc = tid >> 6;
    int mr = blockIdx.x * 64;
    #pragma unroll
    for (int it = 0; it < K / 32; ++it) {
        int idx = (it * 256 + tid) * 8;
        int row = idx / K, col = idx % K;
        int rowg = mr + row; if (rowg > M - 1) rowg = M - 1;
        float4 u0 = *(const float4*)(A + (size_t)rowg * K + col);
        float4 u1 = *(const float4*)(A + (size_t)rowg * K + col + 4);
        f16x8 v;
        v[0] = (_Float16)u0.x; v[1] = (_Float16)u0.y;
        v[2] = (_Float16)u0.z; v[3] = (_Float16)u0.w;
        v[4] = (_Float16)u1.x; v[5] = (_Float16)u1.y;
        v[6] = (_Float16)u1.z; v[7] = (_Float16)u1.w;
        *(f16x8*)(As + row * LDA + col) = v;
    }
    __syncthreads();
    const _Float16* pb[4];
    #pragma unroll
    for (int j = 0; j < 4; ++j) {
        int col = wc * 64 + j * 16 + (lane & 15);
        pb[j] = BT + (size_t)col * K + (lane >> 4) * 8;
    }
    const _Float16* pe = WLRT + (size_t)(lane & 15) * K + (lane >> 4) * 8;
    const _Float16* pa = As + (lane & 15) * LDA + (lane >> 4) * 8;
    f32x4 acc[4][4] = {};
    f32x4 acce[4] = {};
    #pragma unroll
    for (int k0 = 0; k0 < K; k0 += 32) {
        f16x8 a[4], b[4];
        #pragma unroll
        for (int t = 0; t < 4; ++t) a[t] = *(const f16x8*)(pa + t * 16 * LDA + k0);
        #pragma unroll
        for (int t = 0; t < 4; ++t) b[t] = *(const f16x8*)(pb[t] + k0);
        #pragma unroll
        for (int i = 0; i < 4; ++i)
            #pragma unroll
            for (int j = 0; j < 4; ++j)
                acc[i][j] = __builtin_amdgcn_mfma_f32_16x16x32_f16(a[i], b[j], acc[i][j], 0, 0, 0);
        if (wc == 3) {
            f16x8 be = *(const f16x8*)(pe + k0);
            #pragma unroll
            for (int i = 0; i < 4; ++i)
                acce[i] = __builtin_amdgcn_mfma_f32_16x16x32_f16(a[i], be, acce[i], 0, 0, 0);
        }
    }
    #pragma unroll
    for (int i = 0; i < 4; ++i)
        #pragma unroll
        for (int j = 0; j < 4; ++j)
            #pragma unroll
            for (int r = 0; r < 4; ++r) {
                int row = mr + i * 16 + (lane >> 4) * 4 + r;
                int col = wc * 64 + j * 16 + (lane & 15);
                if (row < M) C8[(size_t)row * N + col] = f32_to_fp8(acc[i][j][r]);
            }
    if (wc == 3) {
        int c16 = lane & 15;
        #pragma unroll
        for (int i = 0; i < 4; ++i)
            #pragma unroll
            for (int r = 0; r < 4; ++r) {
                int row = mr + i * 16 + (lane >> 4) * 4 + r;
                if (row < M) {
                    if (c16 < 8) el[row * 8 + c16] = acce[i][r];
                    else         er[row * 8 + (c16 - 8)] = acce[i][r];
                }
            }
    }
}

// ---------- MFMA GEMM, N=256 (layer 1), fp16 A, fp8 out; wave 3 emits el/er ----------
template <int K>
__global__ __launch_bounds__(256) void k_mfma_gemm(const _Float16* __restrict__ A,
                                                   const _Float16* __restrict__ BT,
                                                   const _Float16* __restrict__ WLRT,
                                                   unsigned char* __restrict__ C8,
                                                   float* __restrict__ el,
                                                   float* __restrict__ er, int M) {
    const int N = 256;
    const int LDA = K + 8;
    __shared__ _Float16 As[64 * LDA];
    int tid = threadIdx.x;
    int lane = tid & 63, wc = tid >> 6;
    int mr = blockIdx.x * 64;
    #pragma unroll
    for (int it = 0; it < K / 32; ++it) {
        int idx = (it * 256 + tid) * 8;
        int row = idx / K, col = idx % K;
        int rowg = mr + row; if (rowg > M - 1) rowg = M - 1;
        f16x8 v = *(const f16x8*)(A + (size_t)rowg * K + col);
        *(f16x8*)(As + row * LDA + col) = v;
    }
    __syncthreads();
    const _Float16* pb[4];
    #pragma unroll
    for (int j = 0; j < 4; ++j) {
        int col = wc * 64 + j * 16 + (lane & 15);
        pb[j] = BT + (size_t)col * K + (lane >> 4) * 8;
    }
    const _Float16* pe = WLRT + (size_t)(lane & 15) * K + (lane >> 4) * 8;
    const _Float16* pa = As + (lane & 15) * LDA + (lane >> 4) * 8;
    f32x4 acc[4][4] = {};
    f32x4 acce[4] = {};
    #pragma unroll
    for (int k0 = 0; k0 < K; k0 += 32) {
        f16x8 a[4], b[4];
        #pragma unroll
        for (int t = 0; t < 4; ++t) a[t] = *(const f16x8*)(pa + t * 16 * LDA + k0);
        #pragma unroll
        for (int t = 0; t < 4; ++t) b[t] = *(const f16x8*)(pb[t] + k0);
        #pragma unroll
        for (int i = 0; i < 4; ++i)
            #pragma unroll
            for (int j = 0; j < 4; ++j)
                acc[i][j] = __builtin_amdgcn_mfma_f32_16x16x32_f16(a[i], b[j], acc[i][j], 0, 0, 0);
        if (wc == 3) {
            f16x8 be = *(const f16x8*)(pe + k0);
            #pragma unroll
            for (int i = 0; i < 4; ++i)
                acce[i] = __builtin_amdgcn_mfma_f32_16x16x32_f16(a[i], be, acce[i], 0, 0, 0);
        }
    }
    #pragma unroll
    for (int i = 0; i < 4; ++i)
        #pragma unroll
        for (int j = 0; j < 4; ++j)
            #pragma unroll
            for (int r = 0; r < 4; ++r) {
                int row = mr + i * 16 + (lane >> 4) * 4 + r;
                int col = wc * 64 + j * 16 + (lane & 15);
                if (row < M) C8[(size_t)row * N + col] = f32_to_fp8(acc[i][j][r]);
            }
    if (wc == 3) {
        int c16 = lane & 15;
        #pragma unroll
        for (int i = 0; i < 4; ++i)
            #pragma unroll
            for (int r = 0; r < 4; ++r) {
                int row = mr + i * 16 + (lane >> 4) * 4 + r;
                if (row < M) {
                    if (c16 < 8) el[row * 8 + c16] = acce[i][r];
                    else         er[row * 8 + (c16 - 8)] = acce[i][r];
                }
            }
    }
}

// ---------- MFMA GEMM, N=32 (layer 2), fp16 out, fused el/er via WLR2 ----------
template <int K>
__global__ __launch_bounds__(256) void k_mfma_gemm32(const _Float16* __restrict__ A,
                                                     const _Float16* __restrict__ BT,
                                                     const _Float16* __restrict__ WLRT,
                                                     _Float16* __restrict__ C,
                                                     float* __restrict__ el,
                                                     float* __restrict__ er, int M) {
    const int N = 32;
    int lane = threadIdx.x & 63, w = threadIdx.x >> 6;
    int mr = blockIdx.x * 256 + w * 64;
    const _Float16* pa[4];
    const _Float16* pb[2];
    #pragma unroll
    for (int t = 0; t < 4; ++t) {
        int row = mr + t * 16 + (lane & 15);
        if (row > M - 1) row = M - 1;
        pa[t] = A + (size_t)row * K + (lane >> 4) * 8;
    }
    #pragma unroll
    for (int t = 0; t < 2; ++t) {
        int col = t * 16 + (lane & 15);
        pb[t] = BT + (size_t)col * K + (lane >> 4) * 8;
    }
    const _Float16* pe = WLRT + (size_t)(lane & 15) * K + (lane >> 4) * 8;
    f32x4 acc[4][2] = {};
    f32x4 acce[4] = {};
    #pragma unroll
    for (int k0 = 0; k0 < K; k0 += 32) {
        f16x8 a[4], b[2], be;
        #pragma unroll
        for (int t = 0; t < 4; ++t) a[t] = *(const f16x8*)(pa[t] + k0);
        #pragma unroll
        for (int t = 0; t < 2; ++t) b[t] = *(const f16x8*)(pb[t] + k0);
        be = *(const f16x8*)(pe + k0);
        #pragma unroll
        for (int i = 0; i < 4; ++i) {
            #pragma unroll
            for (int j = 0; j < 2; ++j)
                acc[i][j] = __builtin_amdgcn_mfma_f32_16x16x32_f16(a[i], b[j], acc[i][j], 0, 0, 0);
            acce[i] = __builtin_amdgcn_mfma_f32_16x16x32_f16(a[i], be, acce[i], 0, 0, 0);
        }
    }
    int c16 = lane & 15;
    #pragma unroll
    for (int i = 0; i < 4; ++i)
        #pragma unroll
        for (int r = 0; r < 4; ++r) {
            int row = mr + i * 16 + (lane >> 4) * 4 + r;
            if (row < M) {
                #pragma unroll
                for (int j = 0; j < 2; ++j)
                    C[(size_t)row * N + j * 16 + c16] = (_Float16)acc[i][j][r];
                if (c16 == 0) el[row] = acce[i][r];
                else if (c16 == 1) er[row] = acce[i][r];
            }
        }
}

// ---------- CSR scans ----------
__global__ __launch_bounds__(256) void k_scan1(const int* __restrict__ deg,
                                               int* __restrict__ bsum, int n) {
    int base = blockIdx.x * 1024;
    int t = threadIdx.x;
    int s = 0;
    #pragma unroll
    for (int i = 0; i < 4; ++i) {
        int idx = base + t * 4 + i;
        if (idx < n) s += deg[idx];
    }
    __shared__ int red[256];
    red[t] = s; __syncthreads();
    for (int off = 128; off; off >>= 1) {
        if (t < off) red[t] += red[t + off];
        __syncthreads();
    }
    if (t == 0) bsum[blockIdx.x] = red[0];
}
__global__ __launch_bounds__(256) void k_scan3(const int* __restrict__ deg,
                                               const int* __restrict__ bsum,
                                               int* __restrict__ row_ptr, int n, int E) {
    int base = blockIdx.x * 1024;
    int t = threadIdx.x;
    __shared__ int boff;
    if (t == 0) {
        int s = 0;
        for (int j = 0; j < blockIdx.x; ++j) s += bsum[j];
        boff = s;
        if (blockIdx.x == 0) row_ptr[n] = E;
    }
    int loc[4]; int s = 0;
    #pragma unroll
    for (int i = 0; i < 4; ++i) {
        int idx = base + t * 4 + i;
        loc[i] = (idx < n) ? deg[idx] : 0;
        s += loc[i];
    }
    __shared__ int part[256];
    part[t] = s; __syncthreads();
    for (int off = 1; off < 256; off <<= 1) {
        int v = (t >= off) ? part[t - off] : 0;
        __syncthreads();
        part[t] += v;
        __syncthreads();
    }
    int run = boff + part[t] - s;
    #pragma unroll
    for (int i = 0; i < 4; ++i) {
        int idx = base + t * 4 + i;
        if (idx < n) row_ptr[idx] = run;
        run += loc[i];
    }
}

// ---------- fused softmax aggregation, H=8,C=32: fp8 packed decode, unroll 4 ----------
__global__ __launch_bounds__(256) void k_fused256(const int* __restrict__ row_ptr,
                                                  const int* __restrict__ csrc,
                                                  const float* __restrict__ el,
                                                  const float* __restrict__ er,
                                                  const unsigned char* __restrict__ ft8,
                                                  const float* __restrict__ b,
                                                  _Float16* __restrict__ out, int n) {
    int wave = threadIdx.x >> 6;
    int lane = threadIdx.x & 63;
    int v = blockIdx.x * 4 + wave;
    if (v >= n) return;
    int g = lane >> 4;            // edge slot 0..3
    int l16 = lane & 15;          // channel group: 16 ch each
    int h = l16 >> 1;             // head (2 lanes per head)
    float erv = er[v * 8 + h];
    const float* elh = el + h;
    int e0 = row_ptr[v], e1 = row_ptr[v + 1];
    float s = 0.f;
    f32x2 a[8] = {};
    int k = e0 + g;
    for (; k + 12 < e1; k += 16) {       // 4 edges issued before decode/FMA
        int sn0 = csrc[k];
        int sn1 = csrc[k + 4];
        int sn2 = csrc[k + 8];
        int sn3 = csrc[k + 12];
        float ev0 = elh[sn0 * 8] + erv;
        float ev1 = elh[sn1 * 8] + erv;
        float ev2 = elh[sn2 * 8] + erv;
        float ev3 = elh[sn3 * 8] + erv;
        uint4 q0 = *(const uint4*)(ft8 + ((size_t)sn0 << 8) + l16 * 16);
        uint4 q1 = *(const uint4*)(ft8 + ((size_t)sn1 << 8) + l16 * 16);
        uint4 q2 = *(const uint4*)(ft8 + ((size_t)sn2 << 8) + l16 * 16);
        uint4 q3 = *(const uint4*)(ft8 + ((size_t)sn3 << 8) + l16 * 16);
        ev0 = ev0 > 0.f ? ev0 : 0.2f * ev0;
        ev1 = ev1 > 0.f ? ev1 : 0.2f * ev1;
        ev2 = ev2 > 0.f ? ev2 : 0.2f * ev2;
        ev3 = ev3 > 0.f ? ev3 : 0.2f * ev3;
        float w0 = __expf(ev0), w1 = __expf(ev1), w2 = __expf(ev2), w3 = __expf(ev3);
        s += (w0 + w1) + (w2 + w3);
        acc_edge(a, q0, w0);
        acc_edge(a, q1, w1);
        acc_edge(a, q2, w2);
        acc_edge(a, q3, w3);
    }
    for (; k < e1; k += 4) {
        int sn = csrc[k];
        float ev = elh[sn * 8] + erv;
        ev = ev > 0.f ? ev : 0.2f * ev;
        float w = __expf(ev);
        s += w;
        uint4 q = *(const uint4*)(ft8 + ((size_t)sn << 8) + l16 * 16);
        acc_edge(a, q, w);
    }
    s += __shfl_xor(s, 16, 64);
    s += __shfl_xor(s, 32, 64);
    #pragma unroll
    for (int j = 0; j < 8; ++j) {
        a[j][0] += __shfl_xor(a[j][0], 16, 64);
        a[j][1] += __shfl_xor(a[j][1], 16, 64);
        a[j][0] += __shfl_xor(a[j][0], 32, 64);
        a[j][1] += __shfl_xor(a[j][1], 32, 64);
    }
    if (g == 0) {
        float inv = s > 0.f ? 1.f / s : 0.f;
        const float* bp = b + l16 * 16;
        f16x8 o0, o1;
        #pragma unroll
        for (int j = 0; j < 8; ++j)
            o0[j] = (_Float16)fmaxf(a[j >> 1][j & 1] * inv + bp[j], 0.f);
        #pragma unroll
        for (int j = 0; j < 8; ++j)
            o1[j] = (_Float16)fmaxf(a[(8 + j) >> 1][j & 1] * inv + bp[8 + j], 0.f);
        _Float16* op = out + ((size_t)v << 8) + l16 * 16;
        *(f16x8*)op = o0;
        *(f16x8*)(op + 8) = o1;
    }
}

// ---------- fused aggregation, H=1,C=32 (layer 2) + class softmax (fp16 ft) ----------
__global__ __launch_bounds__(256) void k_fused_out(const int* __restrict__ row_ptr,
                                                   const int* __restrict__ csrc,
                                                   const float* __restrict__ el,
                                                   const float* __restrict__ er,
                                                   const _Float16* __restrict__ ft,
                                                   const float* __restrict__ b,
                                                   float* __restrict__ out, int n) {
    int v = blockIdx.x * 16 + (threadIdx.x >> 4);
    int sub = threadIdx.x & 15;
    int g = sub >> 2;             // edge slot 0..3
    int l4 = sub & 3;             // channel group: 8 ch each
    if (v >= n) return;
    float erv = er[v];
    int e0 = row_ptr[v], e1 = row_ptr[v + 1];
    float s = 0.f;
    float a[8] = {};
    for (int k = e0 + g; k < e1; k += 4) {
        int sn = csrc[k];
        float ev = el[sn] + erv;
        ev = ev > 0.f ? ev : 0.2f * ev;
        float w = __expf(ev);
        s += w;
        f16x8 f = *(const f16x8*)(ft + (sn << 5) + l4 * 8);
        #pragma unroll
        for (int j = 0; j < 8; ++j) a[j] += w * (float)f[j];
    }
    s += __shfl_xor(s, 4, 64);
    s += __shfl_xor(s, 8, 64);
    #pragma unroll
    for (int j = 0; j < 8; ++j) {
        a[j] += __shfl_xor(a[j], 4, 64);
        a[j] += __shfl_xor(a[j], 8, 64);
    }
    float inv = s > 0.f ? 1.f / s : 0.f;
    const float* bp = b + l4 * 8;
    float val[8];
    float mx = -INFINITY;
    #pragma unroll
    for (int j = 0; j < 8; ++j) {
        val[j] = fmaxf(a[j] * inv + bp[j], 0.f);
        mx = fmaxf(mx, val[j]);
    }
    mx = fmaxf(mx, __shfl_xor(mx, 1, 64));
    mx = fmaxf(mx, __shfl_xor(mx, 2, 64));
    float ex[8];
    float sum = 0.f;
    #pragma unroll
    for (int j = 0; j < 8; ++j) { ex[j] = __expf(val[j] - mx); sum += ex[j]; }
    sum += __shfl_xor(sum, 1, 64);
    sum += __shfl_xor(sum, 2, 64);
    float isum = 1.f / sum;
    if (g == 0) {
        float* op = out + ((size_t)v << 5) + l4 * 8;
        *(float4*)op = make_float4(ex[0] * isum, ex[1] * isum, ex[2] * isum, ex[3] * isum);
        *(float4*)(op + 4) = make_float4(ex[4] * isum, ex[5] * isum, ex[6] * isum, ex[7] * isum);
    }
}

extern "C" void kernel_launch(void* const* d_in, const int* in_sizes, int n_in,
                              void* d_out, int out_size, void* d_ws, size_t ws_size,
                              hipStream_t stream) {
    const float* x  = (const float*)d_in[0];
    const int* src  = (const int*)d_in[1];
    const int* dst  = (const int*)d_in[2];
    const float* W0 = (const float*)d_in[3];
    const float* al0 = (const float*)d_in[4];
    const float* ar0 = (const float*)d_in[5];
    const float* b0  = (const float*)d_in[6];
    const float* W1 = (const float*)d_in[7];
    const float* al1 = (const float*)d_in[8];
    const float* ar1 = (const float*)d_in[9];
    const float* b1  = (const float*)d_in[10];
    const float* W2 = (const float*)d_in[11];
    const float* al2 = (const float*)d_in[12];
    const float* ar2 = (const float*)d_in[13];
    const float* b2  = (const float*)d_in[14];
    float* out = (float*)d_out;

    const int n = in_sizes[0] / IN_FEATS;   // 50000
    const int E = in_sizes[1];              // 800000

    // ---- workspace carve (256B-aligned) ----
    char* p = (char*)d_ws;
    auto alloc = [&](size_t bytes) {
        void* r = (void*)p;
        p += (bytes + 255) & ~(size_t)255;
        return r;
    };
    unsigned char* ft8 = (unsigned char*)alloc((size_t)n * 256);   // GEMM out (fp8)
    _Float16* h16   = (_Float16*)alloc((size_t)n * 256 * 2);       // agg out
    _Float16* ft16  = (_Float16*)alloc((size_t)n * 32 * 2);        // layer-2 GEMM out
    _Float16* W0T   = (_Float16*)alloc((size_t)256 * 128 * 2);
    _Float16* W1T   = (_Float16*)alloc((size_t)256 * 256 * 2);
    _Float16* W2T   = (_Float16*)alloc((size_t)32 * 256 * 2);
    _Float16* WLR0  = (_Float16*)alloc((size_t)16 * 128 * 2);
    _Float16* WLR1  = (_Float16*)alloc((size_t)16 * 256 * 2);
    _Float16* WLR2  = (_Float16*)alloc((size_t)16 * 256 * 2);
    float* el       = (float*)alloc((size_t)n * 8 * 4);
    float* er       = (float*)alloc((size_t)n * 8 * 4);
    int* deg        = (int*)alloc((size_t)n * 4);
    int* row_ptr    = (int*)alloc((size_t)(n + 1) * 4);
    int* rank       = (int*)alloc((size_t)E * 4);
    int* csrc       = (int*)alloc((size_t)E * 4);
    int* bsum       = (int*)alloc((size_t)64 * 4);

    const int EB = (E + 255) / 256;          // 3125
    const int FILLB = (E + 1023) / 1024;     // 782 (4 edges/thread)
    const int NBCH = (n + 1023) / 1024;      // 49
    const int GB = (n + 63) / 64;            // 782
    const int GB32 = (n + 255) / 256;
    const int FB = (n + 3) / 4;
    const int OB = (n + 15) / 16;

    // ---- memset deg ----
    hipMemsetAsync(deg, 0, (size_t)n * 4, stream);

    // ---- weight prep ∥ degree+rank ----
    k_degprep<<<456 + EB, 256, 0, stream>>>(W0, W1, W2, al0, ar0, al1, ar1, al2, ar2,
                                            W0T, W1T, W2T, WLR0, WLR1, WLR2,
                                            dst, deg, rank, E);
    k_scan1<<<NBCH, 256, 0, stream>>>(deg, bsum, n);
    k_scan3<<<NBCH, 256, 0, stream>>>(deg, bsum, row_ptr, n, E);

    // ---- layer-0 GEMM ∥ atomic-free CSR fill ----
    k_gemm0_fill<<<GB + FILLB, 256, 0, stream>>>(x, W0T, WLR0, ft8, el, er, n, GB,
                                                 dst, src, row_ptr, rank, csrc, E);
    k_fused256<<<FB, 256, 0, stream>>>(row_ptr, csrc, el, er, ft8, b0, h16, n);

    // ---- layer 1 ----
    k_mfma_gemm<256><<<GB, 256, 0, stream>>>(h16, W1T, WLR1, ft8, el, er, n);
    k_fused256<<<FB, 256, 0, stream>>>(row_ptr, csrc, el, er, ft8, b1, h16, n);

    // ---- layer 2 + class softmax ----
    k_mfma_gemm32<256><<<GB32, 256, 0, stream>>>(h16, W2T, WLR2, ft16, el, er, n);
    k_fused_out<<<OB, 256, 0, stream>>>(row_ptr, csrc, el, er, ft16, b2, out, n);
}